// Round 13
// baseline (151.088 us; speedup 1.0000x reference)
//
#include <hip/hip_runtime.h>
#include <cstdint>
#include <cstddef>

using f16x8 = __attribute__((ext_vector_type(8))) _Float16;
using f32x4 = __attribute__((ext_vector_type(4))) float;

// ---- model constants (f32-rounded from the reference's float64 values) ----
static constexpr float cA1  =  1.1466802242428472f;   // exp(-1/4)+exp(-1)
static constexpr float cA2  = -0.2865047968601901f;   // -exp(-1/4-1)
static constexpr float cV0  =  2.1165347359575991f;   // 4^(4/3)/3
static constexpr float cSIG =  0.7788007830714049f;   // exp(-1/4)

#define TSTEPS 100
#define BATCH  256
#define KPAD   512               // padded feature dim (500 -> 512)
#define MROWS  (TSTEPS * BATCH)  // 25600
#define KS1    7                 // layer-1 K-splits

__device__ __forceinline__ void gload_lds16(const void* g, void* l) {
  __builtin_amdgcn_global_load_lds(
      (void __attribute__((address_space(1)))*)g,
      (void __attribute__((address_space(3)))*)l, 16, 0, 0);
}

// ------- layer-1 f32 GEMM, split-K, with the w2 f16-split folded in --------
#define BM1 64
#define BN1 64
#define BK1 32
#define LDT1 68

__global__ __launch_bounds__(256)
void gemm1_splitk(const float* __restrict__ A, const float* __restrict__ B,
                  float* __restrict__ P,
                  const float* __restrict__ w2,
                  _Float16* __restrict__ Wh, _Float16* __restrict__ Wl) {
  constexpr int M = 256, N = 500, K = 784;
  if (blockIdx.z == KS1) {
    int base = (blockIdx.x + blockIdx.y * 8) * 256 + threadIdx.x;
    for (int idx = base; idx < 512 * 512; idx += 32 * 256) {
      int n = idx >> 9, k = idx & 511;
      float x = (n < 500 && k < 500) ? w2[n * 500 + k] : 0.f;
      _Float16 h = (_Float16)x;                  // RNE
      float r = x - (float)h;                    // exact (Sterbenz)
      Wh[idx] = h;
      Wl[idx] = (_Float16)(r * 4096.f);          // scaled: never subnormal
    }
    return;
  }
  __shared__ float As[BK1][LDT1];
  __shared__ float Bs[BK1][LDT1];
  const int tid = threadIdx.x;
  const int bm  = blockIdx.y * BM1;
  const int bn  = blockIdx.x * BN1;
  const int ks  = blockIdx.z;
  const int k_begin = ks * 128;
  const int k_end   = (k_begin + 128 < K) ? k_begin + 128 : K;
  const int tr  = tid >> 4;
  const int tc  = tid & 15;
  float acc[4][4] = {{0.f}};

  for (int k0 = k_begin; k0 < k_end; k0 += BK1) {
#pragma unroll
    for (int i = 0; i < 2; ++i) {
      const int t = tid + i * 256;
      const int r = t >> 3;
      const int c = (t & 7) << 2;
      const int gk = k0 + c;
      float4 va = make_float4(0.f, 0.f, 0.f, 0.f);
      const int gm = bm + r;
      if (gm < M && gk < k_end) {
        if (gk + 3 < k_end) va = *(const float4*)(A + (size_t)gm * K + gk);
        else {
          const float* p = A + (size_t)gm * K;
          va.x = p[gk];
          if (gk + 1 < k_end) va.y = p[gk + 1];
          if (gk + 2 < k_end) va.z = p[gk + 2];
        }
      }
      As[c + 0][r] = va.x; As[c + 1][r] = va.y;
      As[c + 2][r] = va.z; As[c + 3][r] = va.w;
      float4 vb = make_float4(0.f, 0.f, 0.f, 0.f);
      const int gn = bn + r;
      if (gn < N && gk < k_end) {
        if (gk + 3 < k_end) vb = *(const float4*)(B + (size_t)gn * K + gk);
        else {
          const float* p = B + (size_t)gn * K;
          vb.x = p[gk];
          if (gk + 1 < k_end) vb.y = p[gk + 1];
          if (gk + 2 < k_end) vb.z = p[gk + 2];
        }
      }
      Bs[c + 0][r] = vb.x; Bs[c + 1][r] = vb.y;
      Bs[c + 2][r] = vb.z; Bs[c + 3][r] = vb.w;
    }
    __syncthreads();
#pragma unroll
    for (int kk = 0; kk < BK1; ++kk) {
      const float4 a = *(const float4*)&As[kk][tr * 4];
      const float4 b = *(const float4*)&Bs[kk][tc * 4];
      acc[0][0] += a.x * b.x; acc[0][1] += a.x * b.y; acc[0][2] += a.x * b.z; acc[0][3] += a.x * b.w;
      acc[1][0] += a.y * b.x; acc[1][1] += a.y * b.y; acc[1][2] += a.y * b.z; acc[1][3] += a.y * b.w;
      acc[2][0] += a.z * b.x; acc[2][1] += a.z * b.y; acc[2][2] += a.z * b.z; acc[2][3] += a.z * b.w;
      acc[3][0] += a.w * b.x; acc[3][1] += a.w * b.y; acc[3][2] += a.w * b.z; acc[3][3] += a.w * b.w;
    }
    __syncthreads();
  }
#pragma unroll
  for (int i = 0; i < 4; ++i) {
    const int m = bm + tr * 4 + i;
#pragma unroll
    for (int j = 0; j < 4; ++j) {
      const int n = bn + tc * 4 + j;
      if (n < N) P[((size_t)ks * 256 + m) * 512 + n] = acc[i][j];
    }
  }
}

// ---- layer 1 (reference order), SCALAR threads: one (b,o) per thread ------
__global__ __launch_bounds__(256)
void layer1_split(const float* __restrict__ P,
                  const float* __restrict__ b1,
                  _Float16* __restrict__ Ah,
                  _Float16* __restrict__ Al) {
  int idx = blockIdx.x * 256 + threadIdx.x;      // 0 .. 256*512-1
  int b = idx >> 9, o = idx & 511;
  if (o >= 500) {                                // zero pad cols 500..511
    for (int t = 0; t < TSTEPS; ++t) {
      size_t off = (size_t)(t * BATCH + b) * KPAD + o;
      Ah[off] = (_Float16)0; Al[off] = (_Float16)0;
    }
    return;
  }
  float g = 0.f;
  for (int ks = 0; ks < KS1; ++ks)               // fixed order: deterministic
    g += P[((size_t)ks * 256 + b) * 512 + o];
  const float bb = b1[o];
  float v = 0.f, sp = 0.f, y1 = 0.f, y2 = 0.f;
  float c1 = 0.f, c2 = 0.f;
  for (int t = 0; t < TSTEPS; ++t) {
    float c = cA1 * c1 + cA2 * c2 + cV0; c2 = c1; c1 = c;
    float cur = c * g + bb;
    float vv = cSIG * v * (1.f - sp) + cur;
    float s = (vv > 1.f) ? 1.f : 0.f;
    v = vv; sp = s;
    float y = cA1 * y1 + cA2 * y2 + cV0 * s;
    y2 = y1; y1 = y;
    _Float16 h = (_Float16)y;
    float r = y - (float)h;
    size_t off = (size_t)(t * BATCH + b) * KPAD + o;
    Ah[off] = h;
    Al[off] = (_Float16)(r * 4096.f);
  }
}

// ---- MFMA GEMM2 (R7-proven, FINAL): q2 = y1[M,512] * w2[512,512]^T + b2 ---
// C = Ah*Bh^T + 2^-12*(Ah*Bl^T + Al*Bh^T); BK=64, XOR-swizzled LDS.
// 512 thr / 8 waves (wave tile 64x32); 2 N-jobs per block (grid 400 = one
// resident generation); chunked XCD swizzle. Closed at ~57us: five pipeline
// structures (dbuf, counted-vmcnt, fat-tile, ...) all 57-65us — the split-f16
// dual accumulator (128 unified VGPR) caps occupancy at 2 blk/CU, so the
// 2-phase barrier drain cannot be hidden further at HIP level.
__global__ __launch_bounds__(512, 4)
void gemm2_f16(const _Float16* __restrict__ Ah, const _Float16* __restrict__ Al,
               const _Float16* __restrict__ Bh, const _Float16* __restrict__ Bl,
               const float* __restrict__ bias, float* __restrict__ C) {
  constexpr int K = KPAD;
  __shared__ char smem[4 * 16384];         // 4 planes x 128 rows x 128 B
  char* sAh = smem;
  char* sAl = smem + 16384;
  char* sBh = smem + 32768;
  char* sBl = smem + 49152;

  const int tid  = threadIdx.x;
  const int lane = tid & 63;
  const int wid  = tid >> 6;
  const int wr   = wid >> 2;      // 2 wave-rows
  const int wc   = wid & 3;       // 4 wave-cols
  // XCD-chunked bijective swizzle over 400 blocks (400 % 8 == 0)
  const int orig = blockIdx.x + blockIdx.y * 2;        // 0..399
  const int wg   = (orig & 7) * 50 + (orig >> 3);
  const int bm   = (wg >> 1) * 128;                    // 200 M-tiles
  const int bxl  = wg & 1;                             // N-pair index

  const int lrow = lane & 15;
  const int lkc  = lane >> 4;     // 0..3

#pragma unroll 1
  for (int job = 0; job < 2; ++job) {
    const int bn = (bxl * 2 + job) * 128;

    f32x4 acc0[4][2], acc1[4][2];
#pragma unroll
    for (int m = 0; m < 4; ++m)
#pragma unroll
      for (int n = 0; n < 2; ++n) {
        acc0[m][n] = (f32x4){0.f, 0.f, 0.f, 0.f};
        acc1[m][n] = (f32x4){0.f, 0.f, 0.f, 0.f};
      }

    for (int k0 = 0; k0 < K; k0 += 64) {
      // stage: linear LDS dest; source pre-permuted by the same involution
#pragma unroll
      for (int i = 0; i < 2; ++i) {
        int l = i * 8192 + tid * 16;
        int row = l >> 7;                          // 0..127
        int chunk = ((l >> 4) & 7) ^ (row & 7);    // involutive swizzle
        size_t ga = (size_t)(bm + row) * K + k0 + chunk * 8;
        gload_lds16(Ah + ga, sAh + l);
        gload_lds16(Al + ga, sAl + l);
      }
#pragma unroll
      for (int i = 0; i < 2; ++i) {
        int l = i * 8192 + tid * 16;
        int row = l >> 7;
        int chunk = ((l >> 4) & 7) ^ (row & 7);
        size_t gb = (size_t)(bn + row) * K + k0 + chunk * 8;
        gload_lds16(Bh + gb, sBh + l);
        gload_lds16(Bl + gb, sBl + l);
      }
      __syncthreads();

#pragma unroll
      for (int kh = 0; kh < 2; ++kh) {
        const int kc = kh * 4 + lkc;               // logical 8-elem k-chunk
        f16x8 ah[4], al[4];
#pragma unroll
        for (int m = 0; m < 4; ++m) {
          int row = wr * 64 + m * 16 + lrow;
          int off = row * 128 + ((kc ^ (row & 7)) << 4);
          ah[m] = *(const f16x8*)(sAh + off);
          al[m] = *(const f16x8*)(sAl + off);
        }
#pragma unroll
        for (int n = 0; n < 2; ++n) {
          int row = wc * 32 + n * 16 + lrow;
          int off = row * 128 + ((kc ^ (row & 7)) << 4);
          f16x8 bh = *(const f16x8*)(sBh + off);
          f16x8 bl = *(const f16x8*)(sBl + off);
#pragma unroll
          for (int m = 0; m < 4; ++m) {
            acc0[m][n] = __builtin_amdgcn_mfma_f32_16x16x32_f16(ah[m], bh, acc0[m][n], 0, 0, 0);
            acc1[m][n] = __builtin_amdgcn_mfma_f32_16x16x32_f16(ah[m], bl, acc1[m][n], 0, 0, 0);
            acc1[m][n] = __builtin_amdgcn_mfma_f32_16x16x32_f16(al[m], bh, acc1[m][n], 0, 0, 0);
          }
        }
      }
      __syncthreads();
    }

    // C/D layout: col = lane&15, row = (lane>>4)*4 + reg (m89-verified)
#pragma unroll
    for (int m = 0; m < 4; ++m) {
      int gm0 = bm + wr * 64 + m * 16 + (lane >> 4) * 4;
#pragma unroll
      for (int n = 0; n < 2; ++n) {
        int gn = bn + wc * 32 + n * 16 + (lane & 15);
        float bs = (gn < 500) ? bias[gn] : 0.f;
#pragma unroll
        for (int r = 0; r < 4; ++r)
          C[(size_t)(gm0 + r) * KPAD + gn] =
              acc0[m][n][r] + 0.000244140625f * acc1[m][n][r] + bs;
      }
    }
  }
}

// ---- layer 2 (reference order), SCALAR threads: LIF ; y=IIR(spike) in place
__global__ __launch_bounds__(256)
void lif_mid(float* __restrict__ q) {
  int idx = blockIdx.x * 256 + threadIdx.x;      // 0 .. 256*512-1
  int b = idx >> 9, o = idx & 511;
  if (o >= 500) return;                          // pad cols unused downstream
  float v = 0.f, sp = 0.f, y1 = 0.f, y2 = 0.f;
  for (int t = 0; t < TSTEPS; ++t) {
    size_t off = (size_t)(t * BATCH + b) * KPAD + o;
    float qv = q[off];
    float vv = cSIG * v * (1.f - sp) + qv;
    float s = (vv > 1.f) ? 1.f : 0.f;
    v = vv; sp = s;
    float y = cA1 * y1 + cA2 * y2 + cV0 * s;
    y2 = y1; y1 = y;
    q[off] = y;                                  // same slot, after read
  }
}

// ---- layer-3 GEMM (f32, reference order), grid-stride: 800 blocks,
//      each handles 8 row-groups of 4 (ws3 loaded ONCE per block; k-order
//      and shuffle tree per row identical to before -> bitwise-equal q3) ----
__global__ __launch_bounds__(256)
void gemm3_wave(const float* __restrict__ y, const float* __restrict__ w3,
                float* __restrict__ q3) {
  __shared__ float ws3[10 * 500];
  for (int i = threadIdx.x; i < 5000; i += 256) ws3[i] = w3[i];
  __syncthreads();
  const int wid = threadIdx.x >> 6, lane = threadIdx.x & 63;
#pragma unroll 1
  for (int rep = 0; rep < 8; ++rep) {
    const int m = blockIdx.x * 32 + rep * 4 + wid;
    float p[10];
#pragma unroll
    for (int o = 0; o < 10; ++o) p[o] = 0.f;
    for (int k = lane; k < 500; k += 64) {
      float h = y[(size_t)m * KPAD + k];
#pragma unroll
      for (int o = 0; o < 10; ++o) p[o] += h * ws3[o * 500 + k];
    }
#pragma unroll
    for (int o = 0; o < 10; ++o) {
      float v = p[o];
      for (int off = 32; off; off >>= 1) v += __shfl_down(v, off, 64);
      if (lane == 0) q3[(size_t)m * 10 + o] = v;
    }
  }
}

// ---- output layer: cur3 = q3 + b3 ; LIF ; write [B,10,T] f32 --------------
__global__ __launch_bounds__(64)
void lif_out3(const float* __restrict__ q,
              const float* __restrict__ b3,
              float* __restrict__ out) {
  int idx = blockIdx.x * 64 + threadIdx.x;
  if (idx >= BATCH * 10) return;
  int b = idx / 10, o = idx - b * 10;
  float bb = b3[o];
  float v = 0.f, sp = 0.f;
  for (int t = 0; t < TSTEPS; ++t) {
    float cur = q[(size_t)(t * BATCH + b) * 10 + o] + bb;
    float vv = cSIG * v * (1.f - sp) + cur;
    float s = (vv > 1.f) ? 1.f : 0.f;
    v = vv; sp = s;
    out[(size_t)b * 1000 + (size_t)o * 100 + t] = s;
  }
}

extern "C" void kernel_launch(void* const* d_in, const int* in_sizes, int n_in,
                              void* d_out, int out_size, void* d_ws, size_t ws_size,
                              hipStream_t stream) {
  const float* inputs = (const float*)d_in[0];
  const float* w1 = (const float*)d_in[1];
  const float* b1 = (const float*)d_in[2];
  const float* w2 = (const float*)d_in[3];
  const float* b2 = (const float*)d_in[4];
  const float* w3 = (const float*)d_in[5];
  const float* b3 = (const float*)d_in[6];
  float* out = (float*)d_out;

  char* ws = (char*)d_ws;
  _Float16* w2h = (_Float16*)ws; ws += 512 * 512 * 2;
  _Float16* w2l = (_Float16*)ws; ws += 512 * 512 * 2;
  float* P1 = (float*)ws;        ws += (size_t)KS1 * 256 * 512 * 4;  // 3.67 MB
  float* q2 = (float*)ws;        ws += (size_t)MROWS * KPAD * 4;     // 52.4 MB
  float* q3 = (float*)ws;        ws += (size_t)MROWS * 10 * 4;       // 1.02 MB
  _Float16* Ah = (_Float16*)ws;  ws += (size_t)MROWS * KPAD * 2;     // 26.2 MB
  _Float16* Al = (_Float16*)ws;  ws += (size_t)MROWS * KPAD * 2;     // 26.2 MB
  // total ~110 MB

  // layer 1 split-K GEMM (224 blocks) + w2 f16-split slice (32 blocks)
  gemm1_splitk<<<dim3(8, 4, KS1 + 1), dim3(256), 0, stream>>>(
      inputs, w1, P1, w2, w2h, w2l);
  layer1_split<<<dim3(BATCH * 512 / 256), dim3(256), 0, stream>>>(P1, b1, Ah, Al);

  // layer 2: cur2 = y1 * w2^T + b2 (split-f16 MFMA, swizzled LDS), LIF+IIR
  gemm2_f16<<<dim3(2, 200), dim3(512), 0, stream>>>(Ah, Al, w2h, w2l, b2, q2);
  lif_mid<<<dim3(BATCH * 512 / 256), dim3(256), 0, stream>>>(q2);

  // layer 3: q3 = y2 * w3^T (f32 wave-dot, grid-stride), LIF -> out
  gemm3_wave<<<dim3(MROWS / 32), dim3(256), 0, stream>>>(q2, w3, q3);
  lif_out3<<<dim3((BATCH * 10 + 63) / 64), dim3(64), 0, stream>>>(q3, b3, out);
}

// Round 14
// 145.167 us; speedup vs baseline: 1.0408x; 1.0408x over previous
//
#include <hip/hip_runtime.h>
#include <cstdint>
#include <cstddef>

using f16x8 = __attribute__((ext_vector_type(8))) _Float16;
using f32x4 = __attribute__((ext_vector_type(4))) float;

// ---- model constants (f32-rounded from the reference's float64 values) ----
static constexpr float cA1  =  1.1466802242428472f;   // exp(-1/4)+exp(-1)
static constexpr float cA2  = -0.2865047968601901f;   // -exp(-1/4-1)
static constexpr float cV0  =  2.1165347359575991f;   // 4^(4/3)/3
static constexpr float cSIG =  0.7788007830714049f;   // exp(-1/4)

#define TSTEPS 100
#define BATCH  256
#define KPAD   512               // padded feature dim (500 -> 512)
#define MROWS  (TSTEPS * BATCH)  // 25600
#define KS1    7                 // layer-1 K-splits

__device__ __forceinline__ void gload_lds16(const void* g, void* l) {
  __builtin_amdgcn_global_load_lds(
      (void __attribute__((address_space(1)))*)g,
      (void __attribute__((address_space(3)))*)l, 16, 0, 0);
}

// ------- layer-1 f32 GEMM, split-K, with the w2 f16-split folded in --------
#define BM1 64
#define BN1 64
#define BK1 32
#define LDT1 68

__global__ __launch_bounds__(256)
void gemm1_splitk(const float* __restrict__ A, const float* __restrict__ B,
                  float* __restrict__ P,
                  const float* __restrict__ w2,
                  _Float16* __restrict__ Wh, _Float16* __restrict__ Wl) {
  constexpr int M = 256, N = 500, K = 784;
  if (blockIdx.z == KS1) {
    int base = (blockIdx.x + blockIdx.y * 8) * 256 + threadIdx.x;
    for (int idx = base; idx < 512 * 512; idx += 32 * 256) {
      int n = idx >> 9, k = idx & 511;
      float x = (n < 500 && k < 500) ? w2[n * 500 + k] : 0.f;
      _Float16 h = (_Float16)x;                  // RNE
      float r = x - (float)h;                    // exact (Sterbenz)
      Wh[idx] = h;
      Wl[idx] = (_Float16)(r * 4096.f);          // scaled: never subnormal
    }
    return;
  }
  __shared__ float As[BK1][LDT1];
  __shared__ float Bs[BK1][LDT1];
  const int tid = threadIdx.x;
  const int bm  = blockIdx.y * BM1;
  const int bn  = blockIdx.x * BN1;
  const int ks  = blockIdx.z;
  const int k_begin = ks * 128;
  const int k_end   = (k_begin + 128 < K) ? k_begin + 128 : K;
  const int tr  = tid >> 4;
  const int tc  = tid & 15;
  float acc[4][4] = {{0.f}};

  for (int k0 = k_begin; k0 < k_end; k0 += BK1) {
#pragma unroll
    for (int i = 0; i < 2; ++i) {
      const int t = tid + i * 256;
      const int r = t >> 3;
      const int c = (t & 7) << 2;
      const int gk = k0 + c;
      float4 va = make_float4(0.f, 0.f, 0.f, 0.f);
      const int gm = bm + r;
      if (gm < M && gk < k_end) {
        if (gk + 3 < k_end) va = *(const float4*)(A + (size_t)gm * K + gk);
        else {
          const float* p = A + (size_t)gm * K;
          va.x = p[gk];
          if (gk + 1 < k_end) va.y = p[gk + 1];
          if (gk + 2 < k_end) va.z = p[gk + 2];
        }
      }
      As[c + 0][r] = va.x; As[c + 1][r] = va.y;
      As[c + 2][r] = va.z; As[c + 3][r] = va.w;
      float4 vb = make_float4(0.f, 0.f, 0.f, 0.f);
      const int gn = bn + r;
      if (gn < N && gk < k_end) {
        if (gk + 3 < k_end) vb = *(const float4*)(B + (size_t)gn * K + gk);
        else {
          const float* p = B + (size_t)gn * K;
          vb.x = p[gk];
          if (gk + 1 < k_end) vb.y = p[gk + 1];
          if (gk + 2 < k_end) vb.z = p[gk + 2];
        }
      }
      Bs[c + 0][r] = vb.x; Bs[c + 1][r] = vb.y;
      Bs[c + 2][r] = vb.z; Bs[c + 3][r] = vb.w;
    }
    __syncthreads();
#pragma unroll
    for (int kk = 0; kk < BK1; ++kk) {
      const float4 a = *(const float4*)&As[kk][tr * 4];
      const float4 b = *(const float4*)&Bs[kk][tc * 4];
      acc[0][0] += a.x * b.x; acc[0][1] += a.x * b.y; acc[0][2] += a.x * b.z; acc[0][3] += a.x * b.w;
      acc[1][0] += a.y * b.x; acc[1][1] += a.y * b.y; acc[1][2] += a.y * b.z; acc[1][3] += a.y * b.w;
      acc[2][0] += a.z * b.x; acc[2][1] += a.z * b.y; acc[2][2] += a.z * b.z; acc[2][3] += a.z * b.w;
      acc[3][0] += a.w * b.x; acc[3][1] += a.w * b.y; acc[3][2] += a.w * b.z; acc[3][3] += a.w * b.w;
    }
    __syncthreads();
  }
#pragma unroll
  for (int i = 0; i < 4; ++i) {
    const int m = bm + tr * 4 + i;
#pragma unroll
    for (int j = 0; j < 4; ++j) {
      const int n = bn + tc * 4 + j;
      if (n < N) P[((size_t)ks * 256 + m) * 512 + n] = acc[i][j];
    }
  }
}

// ---- layer 1 (reference order), SCALAR threads: one (b,o) per thread ------
__global__ __launch_bounds__(256)
void layer1_split(const float* __restrict__ P,
                  const float* __restrict__ b1,
                  _Float16* __restrict__ Ah,
                  _Float16* __restrict__ Al) {
  int idx = blockIdx.x * 256 + threadIdx.x;      // 0 .. 256*512-1
  int b = idx >> 9, o = idx & 511;
  if (o >= 500) {                                // zero pad cols 500..511
    for (int t = 0; t < TSTEPS; ++t) {
      size_t off = (size_t)(t * BATCH + b) * KPAD + o;
      Ah[off] = (_Float16)0; Al[off] = (_Float16)0;
    }
    return;
  }
  float g = 0.f;
  for (int ks = 0; ks < KS1; ++ks)               // fixed order: deterministic
    g += P[((size_t)ks * 256 + b) * 512 + o];
  const float bb = b1[o];
  float v = 0.f, sp = 0.f, y1 = 0.f, y2 = 0.f;
  float c1 = 0.f, c2 = 0.f;
  for (int t = 0; t < TSTEPS; ++t) {
    float c = cA1 * c1 + cA2 * c2 + cV0; c2 = c1; c1 = c;
    float cur = c * g + bb;
    float vv = cSIG * v * (1.f - sp) + cur;
    float s = (vv > 1.f) ? 1.f : 0.f;
    v = vv; sp = s;
    float y = cA1 * y1 + cA2 * y2 + cV0 * s;
    y2 = y1; y1 = y;
    _Float16 h = (_Float16)y;
    float r = y - (float)h;
    size_t off = (size_t)(t * BATCH + b) * KPAD + o;
    Ah[off] = h;
    Al[off] = (_Float16)(r * 4096.f);
  }
}

// ---- MFMA GEMM2 (R7-proven, FINAL): q2 = y1[M,512] * w2[512,512]^T + b2 ---
// Closed at ~57us after 5 structural variants (see R12 note).
__global__ __launch_bounds__(512, 4)
void gemm2_f16(const _Float16* __restrict__ Ah, const _Float16* __restrict__ Al,
               const _Float16* __restrict__ Bh, const _Float16* __restrict__ Bl,
               const float* __restrict__ bias, float* __restrict__ C) {
  constexpr int K = KPAD;
  __shared__ char smem[4 * 16384];         // 4 planes x 128 rows x 128 B
  char* sAh = smem;
  char* sAl = smem + 16384;
  char* sBh = smem + 32768;
  char* sBl = smem + 49152;

  const int tid  = threadIdx.x;
  const int lane = tid & 63;
  const int wid  = tid >> 6;
  const int wr   = wid >> 2;      // 2 wave-rows
  const int wc   = wid & 3;       // 4 wave-cols
  // XCD-chunked bijective swizzle over 400 blocks (400 % 8 == 0)
  const int orig = blockIdx.x + blockIdx.y * 2;        // 0..399
  const int wg   = (orig & 7) * 50 + (orig >> 3);
  const int bm   = (wg >> 1) * 128;                    // 200 M-tiles
  const int bxl  = wg & 1;                             // N-pair index

  const int lrow = lane & 15;
  const int lkc  = lane >> 4;     // 0..3

#pragma unroll 1
  for (int job = 0; job < 2; ++job) {
    const int bn = (bxl * 2 + job) * 128;

    f32x4 acc0[4][2], acc1[4][2];
#pragma unroll
    for (int m = 0; m < 4; ++m)
#pragma unroll
      for (int n = 0; n < 2; ++n) {
        acc0[m][n] = (f32x4){0.f, 0.f, 0.f, 0.f};
        acc1[m][n] = (f32x4){0.f, 0.f, 0.f, 0.f};
      }

    for (int k0 = 0; k0 < K; k0 += 64) {
#pragma unroll
      for (int i = 0; i < 2; ++i) {
        int l = i * 8192 + tid * 16;
        int row = l >> 7;                          // 0..127
        int chunk = ((l >> 4) & 7) ^ (row & 7);    // involutive swizzle
        size_t ga = (size_t)(bm + row) * K + k0 + chunk * 8;
        gload_lds16(Ah + ga, sAh + l);
        gload_lds16(Al + ga, sAl + l);
      }
#pragma unroll
      for (int i = 0; i < 2; ++i) {
        int l = i * 8192 + tid * 16;
        int row = l >> 7;
        int chunk = ((l >> 4) & 7) ^ (row & 7);
        size_t gb = (size_t)(bn + row) * K + k0 + chunk * 8;
        gload_lds16(Bh + gb, sBh + l);
        gload_lds16(Bl + gb, sBl + l);
      }
      __syncthreads();

#pragma unroll
      for (int kh = 0; kh < 2; ++kh) {
        const int kc = kh * 4 + lkc;               // logical 8-elem k-chunk
        f16x8 ah[4], al[4];
#pragma unroll
        for (int m = 0; m < 4; ++m) {
          int row = wr * 64 + m * 16 + lrow;
          int off = row * 128 + ((kc ^ (row & 7)) << 4);
          ah[m] = *(const f16x8*)(sAh + off);
          al[m] = *(const f16x8*)(sAl + off);
        }
#pragma unroll
        for (int n = 0; n < 2; ++n) {
          int row = wc * 32 + n * 16 + lrow;
          int off = row * 128 + ((kc ^ (row & 7)) << 4);
          f16x8 bh = *(const f16x8*)(sBh + off);
          f16x8 bl = *(const f16x8*)(sBl + off);
#pragma unroll
          for (int m = 0; m < 4; ++m) {
            acc0[m][n] = __builtin_amdgcn_mfma_f32_16x16x32_f16(ah[m], bh, acc0[m][n], 0, 0, 0);
            acc1[m][n] = __builtin_amdgcn_mfma_f32_16x16x32_f16(ah[m], bl, acc1[m][n], 0, 0, 0);
            acc1[m][n] = __builtin_amdgcn_mfma_f32_16x16x32_f16(al[m], bh, acc1[m][n], 0, 0, 0);
          }
        }
      }
      __syncthreads();
    }

    // C/D layout: col = lane&15, row = (lane>>4)*4 + reg (m89-verified)
#pragma unroll
    for (int m = 0; m < 4; ++m) {
      int gm0 = bm + wr * 64 + m * 16 + (lane >> 4) * 4;
#pragma unroll
      for (int n = 0; n < 2; ++n) {
        int gn = bn + wc * 32 + n * 16 + (lane & 15);
        float bs = (gn < 500) ? bias[gn] : 0.f;
#pragma unroll
        for (int r = 0; r < 4; ++r)
          C[(size_t)(gm0 + r) * KPAD + gn] =
              acc0[m][n][r] + 0.000244140625f * acc1[m][n][r] + bs;
      }
    }
  }
}

// ---- layer 2 (reference order): LIF ; y=IIR(spike) in place ---------------
// Group-of-4 load-ahead: 4 independent loads in flight per thread (G7);
// IIR chain order and all stores bitwise-unchanged.
__global__ __launch_bounds__(256)
void lif_mid(float* __restrict__ q) {
  int idx = blockIdx.x * 256 + threadIdx.x;      // 0 .. 256*512-1
  int b = idx >> 9, o = idx & 511;
  if (o >= 500) return;                          // pad cols unused downstream
  const size_t stride = (size_t)BATCH * KPAD;
  const size_t base = (size_t)b * KPAD + o;
  float v = 0.f, sp = 0.f, y1 = 0.f, y2 = 0.f;
  float buf[4];
#pragma unroll
  for (int j = 0; j < 4; ++j) buf[j] = q[base + (size_t)j * stride];
#pragma unroll 1
  for (int t0 = 0; t0 < TSTEPS; t0 += 4) {
    float nxt[4] = {0.f, 0.f, 0.f, 0.f};
    if (t0 + 4 < TSTEPS) {
#pragma unroll
      for (int j = 0; j < 4; ++j)
        nxt[j] = q[base + (size_t)(t0 + 4 + j) * stride];
    }
#pragma unroll
    for (int j = 0; j < 4; ++j) {
      float qv = buf[j];
      float vv = cSIG * v * (1.f - sp) + qv;
      float s = (vv > 1.f) ? 1.f : 0.f;
      v = vv; sp = s;
      float y = cA1 * y1 + cA2 * y2 + cV0 * s;
      y2 = y1; y1 = y;
      q[base + (size_t)(t0 + j) * stride] = y;
    }
#pragma unroll
    for (int j = 0; j < 4; ++j) buf[j] = nxt[j];
  }
}

// ---- layer-3 GEMM (f32, reference order): q3[m][o] = sum_k y2[m][k]*w3[o][k]
// (R10-proven 6400-block version — R13's grid-stride variant regressed.)
__global__ __launch_bounds__(256)
void gemm3_wave(const float* __restrict__ y, const float* __restrict__ w3,
                float* __restrict__ q3) {
  __shared__ float ws3[10 * 500];
  for (int i = threadIdx.x; i < 5000; i += 256) ws3[i] = w3[i];
  __syncthreads();
  const int wid = threadIdx.x >> 6, lane = threadIdx.x & 63;
  const int m = blockIdx.x * 4 + wid;
  float p[10];
#pragma unroll
  for (int o = 0; o < 10; ++o) p[o] = 0.f;
  for (int k = lane; k < 500; k += 64) {
    float h = y[(size_t)m * KPAD + k];
#pragma unroll
    for (int o = 0; o < 10; ++o) p[o] += h * ws3[o * 500 + k];
  }
#pragma unroll
  for (int o = 0; o < 10; ++o) {
    float v = p[o];
    for (int off = 32; off; off >>= 1) v += __shfl_down(v, off, 64);
    if (lane == 0) q3[(size_t)m * 10 + o] = v;
  }
}

// ---- output layer: cur3 = q3 + b3 ; LIF ; write [B,10,T] f32 --------------
// Group-of-4 load-ahead (2560 threads only — latency is the cost here).
__global__ __launch_bounds__(64)
void lif_out3(const float* __restrict__ q,
              const float* __restrict__ b3,
              float* __restrict__ out) {
  int idx = blockIdx.x * 64 + threadIdx.x;
  if (idx >= BATCH * 10) return;
  int b = idx / 10, o = idx - b * 10;
  const float bb = b3[o];
  const size_t stride = (size_t)BATCH * 10;
  const size_t base = (size_t)b * 10 + o;
  float v = 0.f, sp = 0.f;
  float buf[4];
#pragma unroll
  for (int j = 0; j < 4; ++j) buf[j] = q[base + (size_t)j * stride];
#pragma unroll 1
  for (int t0 = 0; t0 < TSTEPS; t0 += 4) {
    float nxt[4] = {0.f, 0.f, 0.f, 0.f};
    if (t0 + 4 < TSTEPS) {
#pragma unroll
      for (int j = 0; j < 4; ++j)
        nxt[j] = q[base + (size_t)(t0 + 4 + j) * stride];
    }
#pragma unroll
    for (int j = 0; j < 4; ++j) {
      float cur = buf[j] + bb;
      float vv = cSIG * v * (1.f - sp) + cur;
      float s = (vv > 1.f) ? 1.f : 0.f;
      v = vv; sp = s;
      out[(size_t)b * 1000 + (size_t)o * 100 + (t0 + j)] = s;
    }
#pragma unroll
    for (int j = 0; j < 4; ++j) buf[j] = nxt[j];
  }
}

extern "C" void kernel_launch(void* const* d_in, const int* in_sizes, int n_in,
                              void* d_out, int out_size, void* d_ws, size_t ws_size,
                              hipStream_t stream) {
  const float* inputs = (const float*)d_in[0];
  const float* w1 = (const float*)d_in[1];
  const float* b1 = (const float*)d_in[2];
  const float* w2 = (const float*)d_in[3];
  const float* b2 = (const float*)d_in[4];
  const float* w3 = (const float*)d_in[5];
  const float* b3 = (const float*)d_in[6];
  float* out = (float*)d_out;

  char* ws = (char*)d_ws;
  _Float16* w2h = (_Float16*)ws; ws += 512 * 512 * 2;
  _Float16* w2l = (_Float16*)ws; ws += 512 * 512 * 2;
  float* P1 = (float*)ws;        ws += (size_t)KS1 * 256 * 512 * 4;  // 3.67 MB
  float* q2 = (float*)ws;        ws += (size_t)MROWS * KPAD * 4;     // 52.4 MB
  float* q3 = (float*)ws;        ws += (size_t)MROWS * 10 * 4;       // 1.02 MB
  _Float16* Ah = (_Float16*)ws;  ws += (size_t)MROWS * KPAD * 2;     // 26.2 MB
  _Float16* Al = (_Float16*)ws;  ws += (size_t)MROWS * KPAD * 2;     // 26.2 MB
  // total ~110 MB

  // layer 1 split-K GEMM (224 blocks) + w2 f16-split slice (32 blocks)
  gemm1_splitk<<<dim3(8, 4, KS1 + 1), dim3(256), 0, stream>>>(
      inputs, w1, P1, w2, w2h, w2l);
  layer1_split<<<dim3(BATCH * 512 / 256), dim3(256), 0, stream>>>(P1, b1, Ah, Al);

  // layer 2: cur2 = y1 * w2^T + b2 (split-f16 MFMA, swizzled LDS), LIF+IIR
  gemm2_f16<<<dim3(2, 200), dim3(512), 0, stream>>>(Ah, Al, w2h, w2l, b2, q2);
  lif_mid<<<dim3(BATCH * 512 / 256), dim3(256), 0, stream>>>(q2);

  // layer 3: q3 = y2 * w3^T (f32 wave-dot), cur3 = q3 + b3, LIF -> out
  gemm3_wave<<<dim3(MROWS / 4), dim3(256), 0, stream>>>(q2, w3, q3);
  lif_out3<<<dim3((BATCH * 10 + 63) / 64), dim3(64), 0, stream>>>(q3, b3, out);
}

// Round 15
// 138.570 us; speedup vs baseline: 1.0903x; 1.0476x over previous
//
#include <hip/hip_runtime.h>
#include <cstdint>
#include <cstddef>

using f16x8 = __attribute__((ext_vector_type(8))) _Float16;
using f32x4 = __attribute__((ext_vector_type(4))) float;

// ---- model constants (f32-rounded from the reference's float64 values) ----
static constexpr float cA1  =  1.1466802242428472f;   // exp(-1/4)+exp(-1)
static constexpr float cA2  = -0.2865047968601901f;   // -exp(-1/4-1)
static constexpr float cV0  =  2.1165347359575991f;   // 4^(4/3)/3
static constexpr float cSIG =  0.7788007830714049f;   // exp(-1/4)

#define TSTEPS 100
#define BATCH  256
#define KPAD   512               // padded feature dim (500 -> 512)
#define MROWS  (TSTEPS * BATCH)  // 25600
#define KS1    7                 // layer-1 K-splits

__device__ __forceinline__ void gload_lds16(const void* g, void* l) {
  __builtin_amdgcn_global_load_lds(
      (void __attribute__((address_space(1)))*)g,
      (void __attribute__((address_space(3)))*)l, 16, 0, 0);
}

// ------- layer-1 f32 GEMM, split-K, with the w2 f16-split folded in --------
#define BM1 64
#define BN1 64
#define BK1 32
#define LDT1 68

__global__ __launch_bounds__(256)
void gemm1_splitk(const float* __restrict__ A, const float* __restrict__ B,
                  float* __restrict__ P,
                  const float* __restrict__ w2,
                  _Float16* __restrict__ Wh, _Float16* __restrict__ Wl) {
  constexpr int M = 256, N = 500, K = 784;
  if (blockIdx.z == KS1) {
    int base = (blockIdx.x + blockIdx.y * 8) * 256 + threadIdx.x;
    for (int idx = base; idx < 512 * 512; idx += 32 * 256) {
      int n = idx >> 9, k = idx & 511;
      float x = (n < 500 && k < 500) ? w2[n * 500 + k] : 0.f;
      _Float16 h = (_Float16)x;                  // RNE
      float r = x - (float)h;                    // exact (Sterbenz)
      Wh[idx] = h;
      Wl[idx] = (_Float16)(r * 4096.f);          // scaled: never subnormal
    }
    return;
  }
  __shared__ float As[BK1][LDT1];
  __shared__ float Bs[BK1][LDT1];
  const int tid = threadIdx.x;
  const int bm  = blockIdx.y * BM1;
  const int bn  = blockIdx.x * BN1;
  const int ks  = blockIdx.z;
  const int k_begin = ks * 128;
  const int k_end   = (k_begin + 128 < K) ? k_begin + 128 : K;
  const int tr  = tid >> 4;
  const int tc  = tid & 15;
  float acc[4][4] = {{0.f}};

  for (int k0 = k_begin; k0 < k_end; k0 += BK1) {
#pragma unroll
    for (int i = 0; i < 2; ++i) {
      const int t = tid + i * 256;
      const int r = t >> 3;
      const int c = (t & 7) << 2;
      const int gk = k0 + c;
      float4 va = make_float4(0.f, 0.f, 0.f, 0.f);
      const int gm = bm + r;
      if (gm < M && gk < k_end) {
        if (gk + 3 < k_end) va = *(const float4*)(A + (size_t)gm * K + gk);
        else {
          const float* p = A + (size_t)gm * K;
          va.x = p[gk];
          if (gk + 1 < k_end) va.y = p[gk + 1];
          if (gk + 2 < k_end) va.z = p[gk + 2];
        }
      }
      As[c + 0][r] = va.x; As[c + 1][r] = va.y;
      As[c + 2][r] = va.z; As[c + 3][r] = va.w;
      float4 vb = make_float4(0.f, 0.f, 0.f, 0.f);
      const int gn = bn + r;
      if (gn < N && gk < k_end) {
        if (gk + 3 < k_end) vb = *(const float4*)(B + (size_t)gn * K + gk);
        else {
          const float* p = B + (size_t)gn * K;
          vb.x = p[gk];
          if (gk + 1 < k_end) vb.y = p[gk + 1];
          if (gk + 2 < k_end) vb.z = p[gk + 2];
        }
      }
      Bs[c + 0][r] = vb.x; Bs[c + 1][r] = vb.y;
      Bs[c + 2][r] = vb.z; Bs[c + 3][r] = vb.w;
    }
    __syncthreads();
#pragma unroll
    for (int kk = 0; kk < BK1; ++kk) {
      const float4 a = *(const float4*)&As[kk][tr * 4];
      const float4 b = *(const float4*)&Bs[kk][tc * 4];
      acc[0][0] += a.x * b.x; acc[0][1] += a.x * b.y; acc[0][2] += a.x * b.z; acc[0][3] += a.x * b.w;
      acc[1][0] += a.y * b.x; acc[1][1] += a.y * b.y; acc[1][2] += a.y * b.z; acc[1][3] += a.y * b.w;
      acc[2][0] += a.z * b.x; acc[2][1] += a.z * b.y; acc[2][2] += a.z * b.z; acc[2][3] += a.z * b.w;
      acc[3][0] += a.w * b.x; acc[3][1] += a.w * b.y; acc[3][2] += a.w * b.z; acc[3][3] += a.w * b.w;
    }
    __syncthreads();
  }
#pragma unroll
  for (int i = 0; i < 4; ++i) {
    const int m = bm + tr * 4 + i;
#pragma unroll
    for (int j = 0; j < 4; ++j) {
      const int n = bn + tc * 4 + j;
      if (n < N) P[((size_t)ks * 256 + m) * 512 + n] = acc[i][j];
    }
  }
}

// ---- layer 1 (reference order), SCALAR threads: one (b,o) per thread ------
__global__ __launch_bounds__(256)
void layer1_split(const float* __restrict__ P,
                  const float* __restrict__ b1,
                  _Float16* __restrict__ Ah,
                  _Float16* __restrict__ Al) {
  int idx = blockIdx.x * 256 + threadIdx.x;      // 0 .. 256*512-1
  int b = idx >> 9, o = idx & 511;
  if (o >= 500) {                                // zero pad cols 500..511
    for (int t = 0; t < TSTEPS; ++t) {
      size_t off = (size_t)(t * BATCH + b) * KPAD + o;
      Ah[off] = (_Float16)0; Al[off] = (_Float16)0;
    }
    return;
  }
  float g = 0.f;
  for (int ks = 0; ks < KS1; ++ks)               // fixed order: deterministic
    g += P[((size_t)ks * 256 + b) * 512 + o];
  const float bb = b1[o];
  float v = 0.f, sp = 0.f, y1 = 0.f, y2 = 0.f;
  float c1 = 0.f, c2 = 0.f;
  for (int t = 0; t < TSTEPS; ++t) {
    float c = cA1 * c1 + cA2 * c2 + cV0; c2 = c1; c1 = c;
    float cur = c * g + bb;
    float vv = cSIG * v * (1.f - sp) + cur;
    float s = (vv > 1.f) ? 1.f : 0.f;
    v = vv; sp = s;
    float y = cA1 * y1 + cA2 * y2 + cV0 * s;
    y2 = y1; y1 = y;
    _Float16 h = (_Float16)y;
    float r = y - (float)h;
    size_t off = (size_t)(t * BATCH + b) * KPAD + o;
    Ah[off] = h;
    Al[off] = (_Float16)(r * 4096.f);
  }
}

// ---- MFMA GEMM2 (R7-proven, FINAL): q2 = y1[M,512] * w2[512,512]^T + b2 ---
// Closed at ~57us after 5 structural variants (see R12 note).
__global__ __launch_bounds__(512, 4)
void gemm2_f16(const _Float16* __restrict__ Ah, const _Float16* __restrict__ Al,
               const _Float16* __restrict__ Bh, const _Float16* __restrict__ Bl,
               const float* __restrict__ bias, float* __restrict__ C) {
  constexpr int K = KPAD;
  __shared__ char smem[4 * 16384];         // 4 planes x 128 rows x 128 B
  char* sAh = smem;
  char* sAl = smem + 16384;
  char* sBh = smem + 32768;
  char* sBl = smem + 49152;

  const int tid  = threadIdx.x;
  const int lane = tid & 63;
  const int wid  = tid >> 6;
  const int wr   = wid >> 2;      // 2 wave-rows
  const int wc   = wid & 3;       // 4 wave-cols
  // XCD-chunked bijective swizzle over 400 blocks (400 % 8 == 0)
  const int orig = blockIdx.x + blockIdx.y * 2;        // 0..399
  const int wg   = (orig & 7) * 50 + (orig >> 3);
  const int bm   = (wg >> 1) * 128;                    // 200 M-tiles
  const int bxl  = wg & 1;                             // N-pair index

  const int lrow = lane & 15;
  const int lkc  = lane >> 4;     // 0..3

#pragma unroll 1
  for (int job = 0; job < 2; ++job) {
    const int bn = (bxl * 2 + job) * 128;

    f32x4 acc0[4][2], acc1[4][2];
#pragma unroll
    for (int m = 0; m < 4; ++m)
#pragma unroll
      for (int n = 0; n < 2; ++n) {
        acc0[m][n] = (f32x4){0.f, 0.f, 0.f, 0.f};
        acc1[m][n] = (f32x4){0.f, 0.f, 0.f, 0.f};
      }

    for (int k0 = 0; k0 < K; k0 += 64) {
#pragma unroll
      for (int i = 0; i < 2; ++i) {
        int l = i * 8192 + tid * 16;
        int row = l >> 7;                          // 0..127
        int chunk = ((l >> 4) & 7) ^ (row & 7);    // involutive swizzle
        size_t ga = (size_t)(bm + row) * K + k0 + chunk * 8;
        gload_lds16(Ah + ga, sAh + l);
        gload_lds16(Al + ga, sAl + l);
      }
#pragma unroll
      for (int i = 0; i < 2; ++i) {
        int l = i * 8192 + tid * 16;
        int row = l >> 7;
        int chunk = ((l >> 4) & 7) ^ (row & 7);
        size_t gb = (size_t)(bn + row) * K + k0 + chunk * 8;
        gload_lds16(Bh + gb, sBh + l);
        gload_lds16(Bl + gb, sBl + l);
      }
      __syncthreads();

#pragma unroll
      for (int kh = 0; kh < 2; ++kh) {
        const int kc = kh * 4 + lkc;               // logical 8-elem k-chunk
        f16x8 ah[4], al[4];
#pragma unroll
        for (int m = 0; m < 4; ++m) {
          int row = wr * 64 + m * 16 + lrow;
          int off = row * 128 + ((kc ^ (row & 7)) << 4);
          ah[m] = *(const f16x8*)(sAh + off);
          al[m] = *(const f16x8*)(sAl + off);
        }
#pragma unroll
        for (int n = 0; n < 2; ++n) {
          int row = wc * 32 + n * 16 + lrow;
          int off = row * 128 + ((kc ^ (row & 7)) << 4);
          f16x8 bh = *(const f16x8*)(sBh + off);
          f16x8 bl = *(const f16x8*)(sBl + off);
#pragma unroll
          for (int m = 0; m < 4; ++m) {
            acc0[m][n] = __builtin_amdgcn_mfma_f32_16x16x32_f16(ah[m], bh, acc0[m][n], 0, 0, 0);
            acc1[m][n] = __builtin_amdgcn_mfma_f32_16x16x32_f16(ah[m], bl, acc1[m][n], 0, 0, 0);
            acc1[m][n] = __builtin_amdgcn_mfma_f32_16x16x32_f16(al[m], bh, acc1[m][n], 0, 0, 0);
          }
        }
      }
      __syncthreads();
    }

    // C/D layout: col = lane&15, row = (lane>>4)*4 + reg (m89-verified)
#pragma unroll
    for (int m = 0; m < 4; ++m) {
      int gm0 = bm + wr * 64 + m * 16 + (lane >> 4) * 4;
#pragma unroll
      for (int n = 0; n < 2; ++n) {
        int gn = bn + wc * 32 + n * 16 + (lane & 15);
        float bs = (gn < 500) ? bias[gn] : 0.f;
#pragma unroll
        for (int r = 0; r < 4; ++r)
          C[(size_t)(gm0 + r) * KPAD + gn] =
              acc0[m][n][r] + 0.000244140625f * acc1[m][n][r] + bs;
      }
    }
  }
}

// ---- layer 2 (reference order), SCALAR threads: LIF ; y=IIR(spike) in place
// (R10-proven simple version — R14's load-ahead variant regressed.)
__global__ __launch_bounds__(256)
void lif_mid(float* __restrict__ q) {
  int idx = blockIdx.x * 256 + threadIdx.x;      // 0 .. 256*512-1
  int b = idx >> 9, o = idx & 511;
  if (o >= 500) return;                          // pad cols unused downstream
  float v = 0.f, sp = 0.f, y1 = 0.f, y2 = 0.f;
  for (int t = 0; t < TSTEPS; ++t) {
    size_t off = (size_t)(t * BATCH + b) * KPAD + o;
    float qv = q[off];
    float vv = cSIG * v * (1.f - sp) + qv;
    float s = (vv > 1.f) ? 1.f : 0.f;
    v = vv; sp = s;
    float y = cA1 * y1 + cA2 * y2 + cV0 * s;
    y2 = y1; y1 = y;
    q[off] = y;                                  // same slot, after read
  }
}

// ---- layer-3 GEMM (f32, reference order): q3t[(b*10+o)*100+t] = dot -------
// R10-proven 6400-block structure; only the OUTPUT INDEX is permuted to
// [b][o][t] so lif_out3 reads/writes the same contiguous layout as `out`.
__global__ __launch_bounds__(256)
void gemm3_wave(const float* __restrict__ y, const float* __restrict__ w3,
                float* __restrict__ q3t) {
  __shared__ float ws3[10 * 500];
  for (int i = threadIdx.x; i < 5000; i += 256) ws3[i] = w3[i];
  __syncthreads();
  const int wid = threadIdx.x >> 6, lane = threadIdx.x & 63;
  const int m = blockIdx.x * 4 + wid;            // m = t*256 + b
  const int t = m >> 8, b = m & 255;
  float p[10];
#pragma unroll
  for (int o = 0; o < 10; ++o) p[o] = 0.f;
  for (int k = lane; k < 500; k += 64) {
    float h = y[(size_t)m * KPAD + k];
#pragma unroll
    for (int o = 0; o < 10; ++o) p[o] += h * ws3[o * 500 + k];
  }
#pragma unroll
  for (int o = 0; o < 10; ++o) {
    float v = p[o];
    for (int off = 32; off; off >>= 1) v += __shfl_down(v, off, 64);
    if (lane == 0) q3t[((size_t)b * 10 + o) * 100 + t] = v;
  }
}

// ---- output layer: cur3 = q3t + b3 ; LIF ; write [B,10,T] f32 -------------
// q3t layout == out layout: read and write both fully contiguous per thread.
__global__ __launch_bounds__(64)
void lif_out3(const float* __restrict__ q3t,
              const float* __restrict__ b3,
              float* __restrict__ out) {
  int idx = blockIdx.x * 64 + threadIdx.x;
  if (idx >= BATCH * 10) return;
  const int o = idx % 10;
  const float bb = b3[o];
  const size_t base = (size_t)idx * 100;
  float v = 0.f, sp = 0.f;
  for (int t = 0; t < TSTEPS; ++t) {
    float cur = q3t[base + t] + bb;
    float vv = cSIG * v * (1.f - sp) + cur;
    float s = (vv > 1.f) ? 1.f : 0.f;
    v = vv; sp = s;
    out[base + t] = s;
  }
}

extern "C" void kernel_launch(void* const* d_in, const int* in_sizes, int n_in,
                              void* d_out, int out_size, void* d_ws, size_t ws_size,
                              hipStream_t stream) {
  const float* inputs = (const float*)d_in[0];
  const float* w1 = (const float*)d_in[1];
  const float* b1 = (const float*)d_in[2];
  const float* w2 = (const float*)d_in[3];
  const float* b2 = (const float*)d_in[4];
  const float* w3 = (const float*)d_in[5];
  const float* b3 = (const float*)d_in[6];
  float* out = (float*)d_out;

  char* ws = (char*)d_ws;
  _Float16* w2h = (_Float16*)ws; ws += 512 * 512 * 2;
  _Float16* w2l = (_Float16*)ws; ws += 512 * 512 * 2;
  float* P1 = (float*)ws;        ws += (size_t)KS1 * 256 * 512 * 4;  // 3.67 MB
  float* q2 = (float*)ws;        ws += (size_t)MROWS * KPAD * 4;     // 52.4 MB
  float* q3 = (float*)ws;        ws += (size_t)MROWS * 10 * 4;       // 1.02 MB
  _Float16* Ah = (_Float16*)ws;  ws += (size_t)MROWS * KPAD * 2;     // 26.2 MB
  _Float16* Al = (_Float16*)ws;  ws += (size_t)MROWS * KPAD * 2;     // 26.2 MB
  // total ~110 MB

  // layer 1 split-K GEMM (224 blocks) + w2 f16-split slice (32 blocks)
  gemm1_splitk<<<dim3(8, 4, KS1 + 1), dim3(256), 0, stream>>>(
      inputs, w1, P1, w2, w2h, w2l);
  layer1_split<<<dim3(BATCH * 512 / 256), dim3(256), 0, stream>>>(P1, b1, Ah, Al);

  // layer 2: cur2 = y1 * w2^T + b2 (split-f16 MFMA, swizzled LDS), LIF+IIR
  gemm2_f16<<<dim3(2, 200), dim3(512), 0, stream>>>(Ah, Al, w2h, w2l, b2, q2);
  lif_mid<<<dim3(BATCH * 512 / 256), dim3(256), 0, stream>>>(q2);

  // layer 3: q3t = y2 * w3^T (f32 wave-dot, [b][o][t] output), LIF -> out
  gemm3_wave<<<dim3(MROWS / 4), dim3(256), 0, stream>>>(q2, w3, q3);
  lif_out3<<<dim3((BATCH * 10 + 63) / 64), dim3(64), 0, stream>>>(q3, b3, out);
}